// Round 3
// baseline (389.737 us; speedup 1.0000x reference)
//
#include <hip/hip_runtime.h>
#include <float.h>

// x: (B=64, C=256, H=64, W=64) fp32; top-8 per batch over C*H*W; out [B,8,C+3].
#define BB    64
#define CC    256
#define HH    64
#define WW    64
#define K     8
#define NPB   (CC * HH * WW)        // 1048576 elems/batch (2^20)
#define TPB   256
#define OUTC  (CC + 3)              // 259
#define CAP   4096                  // candidate slots per batch (expected ~512)

#define GBLK  2048                  // filter grid: 8 blocks/CU
#define NF4   (BB * NPB / 4)        // 16,777,216 float4 total
#define NITER (NF4 / (GBLK * TPB))  // 32 iterations; 8MB contiguous window/iter

// ---------- helpers ----------

// Total order matching lax.top_k: larger value wins; ties -> lower index wins.
__device__ __forceinline__ bool cand_gt(float v1, int i1, float v2, int i2) {
    return (v1 > v2) || (v1 == v2 && i1 < i2);
}

__device__ __forceinline__ void insert8(float nv, int ni, float (&v)[K], int (&ix)[K]) {
    bool gt[K];
#pragma unroll
    for (int p = 0; p < K; ++p) gt[p] = cand_gt(nv, ni, v[p], ix[p]);
#pragma unroll
    for (int p = K - 1; p > 0; --p) {
        if (gt[p - 1]) { v[p] = v[p - 1]; ix[p] = ix[p - 1]; }
    }
#pragma unroll
    for (int p = 0; p < K; ++p) {
        if (gt[p] && (p == 0 || !gt[p - 1])) { v[p] = nv; ix[p] = ni; }
    }
}

// value-only variant (threshold sample; ties irrelevant)
__device__ __forceinline__ void insertv8(float nv, float (&v)[K]) {
    bool gt[K];
#pragma unroll
    for (int p = 0; p < K; ++p) gt[p] = (nv > v[p]);
#pragma unroll
    for (int p = K - 1; p > 0; --p) {
        if (gt[p - 1]) v[p] = v[p - 1];
    }
#pragma unroll
    for (int p = 0; p < K; ++p) {
        if (gt[p] && (p == 0 || !gt[p - 1])) v[p] = nv;
    }
}

__device__ __forceinline__ void merge_shfl(int d, float (&v)[K], int (&ix)[K]) {
    float ov[K]; int oi[K];
#pragma unroll
    for (int p = 0; p < K; ++p) {
        ov[p] = __shfl_xor(v[p], d, 64);
        oi[p] = __shfl_xor(ix[p], d, 64);
    }
    float mv[K]; int mi[K];
#pragma unroll
    for (int p = 0; p < K; ++p) {
        bool a = cand_gt(v[p], ix[p], ov[K - 1 - p], oi[K - 1 - p]);
        mv[p] = a ? v[p] : ov[K - 1 - p];
        mi[p] = a ? ix[p] : oi[K - 1 - p];
    }
#pragma unroll
    for (int dd = 4; dd >= 1; dd >>= 1) {
#pragma unroll
        for (int i = 0; i < K; ++i) {
            if ((i & dd) == 0) {
                int j = i + dd;
                if (cand_gt(mv[j], mi[j], mv[i], mi[i])) {
                    float tv = mv[i]; mv[i] = mv[j]; mv[j] = tv;
                    int   ti = mi[i]; mi[i] = mi[j]; mi[j] = ti;
                }
            }
        }
    }
#pragma unroll
    for (int p = 0; p < K; ++p) { v[p] = mv[p]; ix[p] = mi[p]; }
}

__device__ __forceinline__ void merge_shfl_v(int d, float (&v)[K]) {
    float ov[K];
#pragma unroll
    for (int p = 0; p < K; ++p) ov[p] = __shfl_xor(v[p], d, 64);
    float mv[K];
#pragma unroll
    for (int p = 0; p < K; ++p) mv[p] = fmaxf(v[p], ov[K - 1 - p]);
#pragma unroll
    for (int dd = 4; dd >= 1; dd >>= 1) {
#pragma unroll
        for (int i = 0; i < K; ++i) {
            if ((i & dd) == 0) {
                int j = i + dd;
                float lo = fminf(mv[i], mv[j]);
                mv[i] = fmaxf(mv[i], mv[j]);
                mv[j] = lo;
            }
        }
    }
#pragma unroll
    for (int p = 0; p < K; ++p) v[p] = mv[p];
}

// ---------- kernel 1: per-batch valid threshold from a 16K-element subset ----------
// 8th largest of any subset <= 8th largest of full set -> nothing true is filtered.
// Also zeroes cnt (runs before filter_cand in stream order).
__global__ __launch_bounds__(TPB) void sample_thresh(const float* __restrict__ x,
                                                     float* __restrict__ thr,
                                                     int* __restrict__ cnt) {
    const int b = blockIdx.x;
    const int t = threadIdx.x;
    if (t == 0) cnt[b] = 0;

    float v[K];
#pragma unroll
    for (int p = 0; p < K; ++p) v[p] = -FLT_MAX;

    // contiguous 64KB region: first 16384 elements of batch b
    const float4* xb = reinterpret_cast<const float4*>(x + (size_t)b * NPB);
#pragma unroll
    for (int c = 0; c < 16; ++c) {
        const float4 f = xb[c * TPB + t];
        if (f.x > v[K - 1]) insertv8(f.x, v);
        if (f.y > v[K - 1]) insertv8(f.y, v);
        if (f.z > v[K - 1]) insertv8(f.z, v);
        if (f.w > v[K - 1]) insertv8(f.w, v);
    }

    __shared__ float sv[TPB * K];
#pragma unroll
    for (int p = 0; p < K; ++p) sv[p * TPB + t] = v[p];
    __syncthreads();

    if (t < 64) {
        float mv[K];
#pragma unroll
        for (int p = 0; p < K; ++p) mv[p] = -FLT_MAX;
        for (int j = t; j < TPB * K; j += 64) {
            if (sv[j] > mv[K - 1]) insertv8(sv[j], mv);
        }
        merge_shfl_v(1, mv);  merge_shfl_v(2, mv);  merge_shfl_v(4, mv);
        merge_shfl_v(8, mv);  merge_shfl_v(16, mv); merge_shfl_v(32, mv);
        if (t == 0) thr[b] = mv[K - 1];
    }
}

// ---------- kernel 2: linear grid-stride filter over the whole array ----------
// Per iteration the chip reads ONE contiguous 8MB window (GBLK*TPB*16B) ->
// uniform HBM channel coverage (m13 copy-bench pattern), unlike the previous
// 128KB-chunk-per-block layout whose in-phase strides aliased channels.
__global__ __launch_bounds__(TPB) void filter_cand(const float4* __restrict__ x4,
                                                   const float* __restrict__ thr,
                                                   float* __restrict__ cval,
                                                   int* __restrict__ cidx,
                                                   int* __restrict__ cnt) {
    __shared__ float sthr[BB];
    const int t = threadIdx.x;
    if (t < BB) sthr[t] = thr[t];
    __syncthreads();

    const int tid = blockIdx.x * TPB + t;
#pragma unroll 8
    for (int it = 0; it < NITER; ++it) {
        const int g = it * (GBLK * TPB) + tid;     // float4 index, fully linear
        const float4 f = x4[g];
        const int b = g >> 18;                     // 2^18 float4 per batch
        const float T = sthr[b];                   // LDS broadcast (wave-uniform)
        const float m = fmaxf(fmaxf(f.x, f.y), fmaxf(f.z, f.w));
        if (m >= T) {                              // rare: ~1/512 per lane-iter
            const float vals[4] = {f.x, f.y, f.z, f.w};
            const int e0 = (g << 2) & (NPB - 1);   // element offset within batch
#pragma unroll
            for (int j = 0; j < 4; ++j) {
                if (vals[j] >= T) {
                    const int o = atomicAdd(&cnt[b], 1);
                    if (o < CAP) {
                        cval[(size_t)b * CAP + o] = vals[j];
                        cidx[(size_t)b * CAP + o] = e0 + j;
                    }
                }
            }
        }
    }
}

// ---------- kernel 3: exact top-8 over <=CAP candidates; emit output rows ----------
__global__ __launch_bounds__(TPB) void final_select(const float* __restrict__ cval,
                                                    const int* __restrict__ cidx,
                                                    const int* __restrict__ cnt,
                                                    float* __restrict__ out) {
    const int b = blockIdx.x;
    const int t = threadIdx.x;
    const int n = min(cnt[b], CAP);

    float v[K]; int ix[K];
#pragma unroll
    for (int p = 0; p < K; ++p) { v[p] = -FLT_MAX; ix[p] = 0x7fffffff; }
    const float* cv = cval + (size_t)b * CAP;
    const int*   ci = cidx + (size_t)b * CAP;
    for (int j = t; j < n; j += TPB) {
        const float nv = cv[j]; const int ni = ci[j];
        if (cand_gt(nv, ni, v[K - 1], ix[K - 1])) insert8(nv, ni, v, ix);
    }

    // zero this batch's output block (d_out is poisoned)
    float* ob = out + (size_t)b * K * OUTC;
    for (int j = t; j < K * OUTC; j += TPB) ob[j] = 0.0f;

    __shared__ float sv[TPB * K];
    __shared__ int   si[TPB * K];
#pragma unroll
    for (int p = 0; p < K; ++p) { sv[p * TPB + t] = v[p]; si[p * TPB + t] = ix[p]; }
    __syncthreads();

    if (t < 64) {
        float mv[K]; int mi[K];
#pragma unroll
        for (int p = 0; p < K; ++p) { mv[p] = -FLT_MAX; mi[p] = 0x7fffffff; }
        for (int j = t; j < TPB * K; j += 64) {
            const float nv = sv[j]; const int ni = si[j];
            if (cand_gt(nv, ni, mv[K - 1], mi[K - 1])) insert8(nv, ni, mv, mi);
        }
        merge_shfl(1, mv, mi);  merge_shfl(2, mv, mi);  merge_shfl(4, mv, mi);
        merge_shfl(8, mv, mi);  merge_shfl(16, mv, mi); merge_shfl(32, mv, mi);
        if (t == 0) {
#pragma unroll
            for (int r = 0; r < K; ++r) {
                const int idx = mi[r];
                const int c   = idx >> 12;       // /4096
                const int rem = idx & 4095;
                const int yy  = rem >> 6;
                const int xx  = rem & 63;
                float* row = ob + r * OUTC;
                row[c]      = 1.0f;
                row[CC]     = mv[r];
                row[CC + 1] = (float)xx / 63.0f;
                row[CC + 2] = (float)yy / 63.0f;
            }
        }
    }
}

// ---------- launch ----------

extern "C" void kernel_launch(void* const* d_in, const int* in_sizes, int n_in,
                              void* d_out, int out_size, void* d_ws, size_t ws_size,
                              hipStream_t stream) {
    const float* x = (const float*)d_in[0];
    float* out = (float*)d_out;

    // ws layout: cval BB*CAP f32 | cidx BB*CAP i32 | cnt BB i32 | thr BB f32
    float* cval = (float*)d_ws;
    int*   cidx = (int*)((char*)d_ws + (size_t)BB * CAP * sizeof(float));
    int*   cnt  = (int*)((char*)d_ws + (size_t)BB * CAP * 8);
    float* thr  = (float*)((char*)cnt + 256);

    sample_thresh<<<BB, TPB, 0, stream>>>(x, thr, cnt);
    filter_cand<<<GBLK, TPB, 0, stream>>>(reinterpret_cast<const float4*>(x),
                                          thr, cval, cidx, cnt);
    final_select<<<BB, TPB, 0, stream>>>(cval, cidx, cnt, out);
}

// Round 4
// 262.956 us; speedup vs baseline: 1.4821x; 1.4821x over previous
//
#include <hip/hip_runtime.h>
#include <float.h>

// x: (B=64, C=256, H=64, W=64) fp32; top-8 per batch over C*H*W; out [B,8,C+3].
#define BB    64
#define CC    256
#define HH    64
#define WW    64
#define K     8
#define NPB   (CC * HH * WW)        // 1048576 elems/batch (2^20)
#define TPB   256
#define OUTC  (CC + 3)              // 259
#define CAP   4096                  // candidate slots per batch (expected ~512)
#define NBLK  32                    // filter blocks per batch (chunk-per-block: best so far)
#define CHUNK (NPB / NBLK)          // 32768 elems = 8192 float4 per block
#define MLP   8                     // batched independent loads per wave-iter
#define OITER (CHUNK / 4 / (TPB * MLP))  // 4 outer iterations

// ---------- helpers ----------

// Total order matching lax.top_k: larger value wins; ties -> lower index wins.
__device__ __forceinline__ bool cand_gt(float v1, int i1, float v2, int i2) {
    return (v1 > v2) || (v1 == v2 && i1 < i2);
}

__device__ __forceinline__ void insert8(float nv, int ni, float (&v)[K], int (&ix)[K]) {
    bool gt[K];
#pragma unroll
    for (int p = 0; p < K; ++p) gt[p] = cand_gt(nv, ni, v[p], ix[p]);
#pragma unroll
    for (int p = K - 1; p > 0; --p) {
        if (gt[p - 1]) { v[p] = v[p - 1]; ix[p] = ix[p - 1]; }
    }
#pragma unroll
    for (int p = 0; p < K; ++p) {
        if (gt[p] && (p == 0 || !gt[p - 1])) { v[p] = nv; ix[p] = ni; }
    }
}

// value-only variant (threshold sample; ties irrelevant)
__device__ __forceinline__ void insertv8(float nv, float (&v)[K]) {
    bool gt[K];
#pragma unroll
    for (int p = 0; p < K; ++p) gt[p] = (nv > v[p]);
#pragma unroll
    for (int p = K - 1; p > 0; --p) {
        if (gt[p - 1]) v[p] = v[p - 1];
    }
#pragma unroll
    for (int p = 0; p < K; ++p) {
        if (gt[p] && (p == 0 || !gt[p - 1])) v[p] = nv;
    }
}

__device__ __forceinline__ void merge_shfl(int d, float (&v)[K], int (&ix)[K]) {
    float ov[K]; int oi[K];
#pragma unroll
    for (int p = 0; p < K; ++p) {
        ov[p] = __shfl_xor(v[p], d, 64);
        oi[p] = __shfl_xor(ix[p], d, 64);
    }
    float mv[K]; int mi[K];
#pragma unroll
    for (int p = 0; p < K; ++p) {
        bool a = cand_gt(v[p], ix[p], ov[K - 1 - p], oi[K - 1 - p]);
        mv[p] = a ? v[p] : ov[K - 1 - p];
        mi[p] = a ? ix[p] : oi[K - 1 - p];
    }
#pragma unroll
    for (int dd = 4; dd >= 1; dd >>= 1) {
#pragma unroll
        for (int i = 0; i < K; ++i) {
            if ((i & dd) == 0) {
                int j = i + dd;
                if (cand_gt(mv[j], mi[j], mv[i], mi[i])) {
                    float tv = mv[i]; mv[i] = mv[j]; mv[j] = tv;
                    int   ti = mi[i]; mi[i] = mi[j]; mi[j] = ti;
                }
            }
        }
    }
#pragma unroll
    for (int p = 0; p < K; ++p) { v[p] = mv[p]; ix[p] = mi[p]; }
}

__device__ __forceinline__ void merge_shfl_v(int d, float (&v)[K]) {
    float ov[K];
#pragma unroll
    for (int p = 0; p < K; ++p) ov[p] = __shfl_xor(v[p], d, 64);
    float mv[K];
#pragma unroll
    for (int p = 0; p < K; ++p) mv[p] = fmaxf(v[p], ov[K - 1 - p]);
#pragma unroll
    for (int dd = 4; dd >= 1; dd >>= 1) {
#pragma unroll
        for (int i = 0; i < K; ++i) {
            if ((i & dd) == 0) {
                int j = i + dd;
                float lo = fminf(mv[i], mv[j]);
                mv[i] = fmaxf(mv[i], mv[j]);
                mv[j] = lo;
            }
        }
    }
#pragma unroll
    for (int p = 0; p < K; ++p) v[p] = mv[p];
}

// ---------- kernel 1: per-batch valid threshold from a 16K-element subset ----------
// 8th largest of any subset <= 8th largest of full set -> nothing true is filtered.
// Also zeroes cnt (runs before filter_cand in stream order).
__global__ __launch_bounds__(TPB) void sample_thresh(const float* __restrict__ x,
                                                     float* __restrict__ thr,
                                                     int* __restrict__ cnt) {
    const int b = blockIdx.x;
    const int t = threadIdx.x;
    if (t == 0) cnt[b] = 0;

    float v[K];
#pragma unroll
    for (int p = 0; p < K; ++p) v[p] = -FLT_MAX;

    // contiguous 64KB region: first 16384 elements of batch b; batched loads (MLP=8)
    const float4* xb = reinterpret_cast<const float4*>(x + (size_t)b * NPB);
#pragma unroll 1
    for (int c2 = 0; c2 < 2; ++c2) {
        float4 f[MLP];
#pragma unroll
        for (int j = 0; j < MLP; ++j) f[j] = xb[(c2 * MLP + j) * TPB + t];
#pragma unroll
        for (int j = 0; j < MLP; ++j) {
            if (f[j].x > v[K - 1]) insertv8(f[j].x, v);
            if (f[j].y > v[K - 1]) insertv8(f[j].y, v);
            if (f[j].z > v[K - 1]) insertv8(f[j].z, v);
            if (f[j].w > v[K - 1]) insertv8(f[j].w, v);
        }
    }

    __shared__ float sv[TPB * K];
#pragma unroll
    for (int p = 0; p < K; ++p) sv[p * TPB + t] = v[p];
    __syncthreads();

    if (t < 64) {
        float mv[K];
#pragma unroll
        for (int p = 0; p < K; ++p) mv[p] = -FLT_MAX;
        for (int j = t; j < TPB * K; j += 64) {
            if (sv[j] > mv[K - 1]) insertv8(sv[j], mv);
        }
        merge_shfl_v(1, mv);  merge_shfl_v(2, mv);  merge_shfl_v(4, mv);
        merge_shfl_v(8, mv);  merge_shfl_v(16, mv); merge_shfl_v(32, mv);
        if (t == 0) thr[b] = mv[K - 1];
    }
}

// ---------- kernel 2: filter, chunk-per-block (R2 layout) + batched loads ----------
// Each iteration: 8 independent global_load_dwordx4 into registers (8KB/wave in
// flight), THEN consume. Raises per-wave MLP from 1 (R2: VGPR=8, one load
// outstanding -> latency-bound at 1.6 TB/s) to 8.
__global__ __launch_bounds__(TPB) void filter_cand(const float4* __restrict__ x4,
                                                   const float* __restrict__ thr,
                                                   float* __restrict__ cval,
                                                   int* __restrict__ cidx,
                                                   int* __restrict__ cnt) {
    const int b   = blockIdx.x / NBLK;
    const int blk = blockIdx.x % NBLK;
    const int t   = threadIdx.x;
    const float T = thr[b];                       // block-uniform -> scalar
    const float4* xb = x4 + ((size_t)b * NPB + (size_t)blk * CHUNK) / 4;
    const int base = blk * CHUNK;                 // element offset within batch

#pragma unroll 1
    for (int it = 0; it < OITER; ++it) {
        float4 f[MLP];
#pragma unroll
        for (int j = 0; j < MLP; ++j)
            f[j] = xb[(it * MLP + j) * TPB + t];  // 8 independent coalesced loads
#pragma unroll
        for (int j = 0; j < MLP; ++j) {
            const float m = fmaxf(fmaxf(f[j].x, f[j].y), fmaxf(f[j].z, f[j].w));
            if (m >= T) {                         // rare: ~1/512 per lane-iter
                const float vals[4] = {f[j].x, f[j].y, f[j].z, f[j].w};
                const int e0 = base + ((it * MLP + j) * TPB + t) * 4;
#pragma unroll
                for (int q = 0; q < 4; ++q) {
                    if (vals[q] >= T) {
                        const int o = atomicAdd(&cnt[b], 1);
                        if (o < CAP) {
                            cval[(size_t)b * CAP + o] = vals[q];
                            cidx[(size_t)b * CAP + o] = e0 + q;
                        }
                    }
                }
            }
        }
    }
}

// ---------- kernel 3: exact top-8 over <=CAP candidates; emit output rows ----------
__global__ __launch_bounds__(TPB) void final_select(const float* __restrict__ cval,
                                                    const int* __restrict__ cidx,
                                                    const int* __restrict__ cnt,
                                                    float* __restrict__ out) {
    const int b = blockIdx.x;
    const int t = threadIdx.x;
    const int n = min(cnt[b], CAP);

    float v[K]; int ix[K];
#pragma unroll
    for (int p = 0; p < K; ++p) { v[p] = -FLT_MAX; ix[p] = 0x7fffffff; }
    const float* cv = cval + (size_t)b * CAP;
    const int*   ci = cidx + (size_t)b * CAP;
    for (int j = t; j < n; j += TPB) {
        const float nv = cv[j]; const int ni = ci[j];
        if (cand_gt(nv, ni, v[K - 1], ix[K - 1])) insert8(nv, ni, v, ix);
    }

    // zero this batch's output block (d_out is poisoned)
    float* ob = out + (size_t)b * K * OUTC;
    for (int j = t; j < K * OUTC; j += TPB) ob[j] = 0.0f;

    __shared__ float sv[TPB * K];
    __shared__ int   si[TPB * K];
#pragma unroll
    for (int p = 0; p < K; ++p) { sv[p * TPB + t] = v[p]; si[p * TPB + t] = ix[p]; }
    __syncthreads();

    if (t < 64) {
        float mv[K]; int mi[K];
#pragma unroll
        for (int p = 0; p < K; ++p) { mv[p] = -FLT_MAX; mi[p] = 0x7fffffff; }
        for (int j = t; j < TPB * K; j += 64) {
            const float nv = sv[j]; const int ni = si[j];
            if (cand_gt(nv, ni, mv[K - 1], mi[K - 1])) insert8(nv, ni, mv, mi);
        }
        merge_shfl(1, mv, mi);  merge_shfl(2, mv, mi);  merge_shfl(4, mv, mi);
        merge_shfl(8, mv, mi);  merge_shfl(16, mv, mi); merge_shfl(32, mv, mi);
        if (t == 0) {
#pragma unroll
            for (int r = 0; r < K; ++r) {
                const int idx = mi[r];
                const int c   = idx >> 12;       // /4096
                const int rem = idx & 4095;
                const int yy  = rem >> 6;
                const int xx  = rem & 63;
                float* row = ob + r * OUTC;
                row[c]      = 1.0f;
                row[CC]     = mv[r];
                row[CC + 1] = (float)xx / 63.0f;
                row[CC + 2] = (float)yy / 63.0f;
            }
        }
    }
}

// ---------- launch ----------

extern "C" void kernel_launch(void* const* d_in, const int* in_sizes, int n_in,
                              void* d_out, int out_size, void* d_ws, size_t ws_size,
                              hipStream_t stream) {
    const float* x = (const float*)d_in[0];
    float* out = (float*)d_out;

    // ws layout: cval BB*CAP f32 | cidx BB*CAP i32 | cnt BB i32 | thr BB f32
    float* cval = (float*)d_ws;
    int*   cidx = (int*)((char*)d_ws + (size_t)BB * CAP * sizeof(float));
    int*   cnt  = (int*)((char*)d_ws + (size_t)BB * CAP * 8);
    float* thr  = (float*)((char*)cnt + 256);

    sample_thresh<<<BB, TPB, 0, stream>>>(x, thr, cnt);
    filter_cand<<<BB * NBLK, TPB, 0, stream>>>(reinterpret_cast<const float4*>(x),
                                               thr, cval, cidx, cnt);
    final_select<<<BB, TPB, 0, stream>>>(cval, cidx, cnt, out);
}